// Round 15
// baseline (323.510 us; speedup 1.0000x reference)
//
#include <hip/hip_runtime.h>
#include <hip/hip_bf16.h>
#include <stdint.h>

typedef __bf16 bf16;
typedef __attribute__((ext_vector_type(8))) __bf16 bf16x8;
typedef __attribute__((ext_vector_type(4))) float f32x4;

static constexpr int kTok = 4096;    // B*S
static constexpr int kHid = 1024;
static constexpr int kInter = 4096;

// async global->LDS, 16B/lane. LDS arg must be wave-uniform base; HW adds
// lane*16. Global arg is per-lane.
#define GLDS16(g, l)                                                \
  __builtin_amdgcn_global_load_lds(                                 \
      (const __attribute__((address_space(1))) void*)(g),           \
      (__attribute__((address_space(3))) void*)(l), 16, 0, 0)

// ---------------- fused: router GEMM (head) + fp32->bf16 convert ----------
// bid < 32       : router block (fp32 staged inline, reads X/Wr -> out1).
// 32 <= bid<8224 : cvt slice c=bid-32: c>>11 = 0:X 1:Wg 2:Wu 3:Wd.
// bid >= 8224    : expert-table cvt (dE/uE -> bf16), only when bigws.
__global__ void __launch_bounds__(256) k_cvt_rt(
    const float* X, const float* Wg, const float* Wu, const float* Wd,
    const float* Wr, const float* dE, const float* uE,
    bf16* Xb, bf16* Wgb, bf16* Wub, bf16* Wdb, bf16* dEb, bf16* uEb,
    float* out1) {
  __shared__ bf16 smem[8192];  // router only (16 KiB)
  const int bid = blockIdx.x;
  const int t = threadIdx.x;

  if (bid < 32) {
    // ---- router: C(4096x128) = X(4096x1024) * Wr(128x1024)^T ----
    const int w = t >> 6;
    const int L = t & 63;
    const int la = L & 15;
    const int lk = (L >> 4) * 8;
    bf16* sA = smem;           // 128x32
    bf16* sB = smem + 4096;    // 128x32
    const long m0 = (long)bid * 128;
    const int wm = (w >> 1) * 64;
    const int wn = (w & 1) * 64;
    const f32x4 fzero = {0.f, 0.f, 0.f, 0.f};
    f32x4 acc[4][4];
#pragma unroll
    for (int i = 0; i < 4; ++i)
#pragma unroll
      for (int j = 0; j < 4; ++j) acc[i][j] = fzero;

    const int c0 = t, c1 = t + 256;
    const long ar0 = m0 + (c0 >> 2), ar1 = m0 + (c1 >> 2);
    const long br0 = (c0 >> 2), br1 = (c1 >> 2);
    const int ko = (c0 & 3) * 8;
    const bf16* sAr = sA + (wm + la) * 32 + lk;
    const bf16* sBr = sB + (wn + la) * 32 + lk;

    for (int kt = 0; kt < 32; ++kt) {
      const long k0 = (long)kt << 5;
      bf16x8 av0, av1, bv0, bv1;
      {
        const f32x4 x0 = *(const f32x4*)(X + ar0 * kHid + k0 + ko);
        const f32x4 x1 = *(const f32x4*)(X + ar0 * kHid + k0 + ko + 4);
        const f32x4 y0 = *(const f32x4*)(X + ar1 * kHid + k0 + ko);
        const f32x4 y1 = *(const f32x4*)(X + ar1 * kHid + k0 + ko + 4);
        const f32x4 p0 = *(const f32x4*)(Wr + br0 * kHid + k0 + ko);
        const f32x4 p1 = *(const f32x4*)(Wr + br0 * kHid + k0 + ko + 4);
        const f32x4 q0 = *(const f32x4*)(Wr + br1 * kHid + k0 + ko);
        const f32x4 q1 = *(const f32x4*)(Wr + br1 * kHid + k0 + ko + 4);
#pragma unroll
        for (int i = 0; i < 4; ++i) {
          av0[i] = (bf16)x0[i]; av0[4 + i] = (bf16)x1[i];
          av1[i] = (bf16)y0[i]; av1[4 + i] = (bf16)y1[i];
          bv0[i] = (bf16)p0[i]; bv0[4 + i] = (bf16)p1[i];
          bv1[i] = (bf16)q0[i]; bv1[4 + i] = (bf16)q1[i];
        }
      }
      __syncthreads();
      *(bf16x8*)(sA + c0 * 8) = av0;
      *(bf16x8*)(sA + c1 * 8) = av1;
      *(bf16x8*)(sB + c0 * 8) = bv0;
      *(bf16x8*)(sB + c1 * 8) = bv1;
      __syncthreads();
      bf16x8 af[4], bfm[4];
#pragma unroll
      for (int i = 0; i < 4; ++i) {
        af[i] = *(const bf16x8*)(sAr + i * 512);
        bfm[i] = *(const bf16x8*)(sBr + i * 512);
      }
#pragma unroll
      for (int i = 0; i < 4; ++i)
#pragma unroll
        for (int j = 0; j < 4; ++j)
          acc[i][j] = __builtin_amdgcn_mfma_f32_16x16x32_bf16(
              af[i], bfm[j], acc[i][j], 0, 0, 0);
    }
    const long col0 = wn + la;
    const long row0 = m0 + wm + (L >> 4) * 4;
#pragma unroll
    for (int i = 0; i < 4; ++i)
#pragma unroll
      for (int j = 0; j < 4; ++j)
#pragma unroll
        for (int r = 0; r < 4; ++r)
          out1[(row0 + i * 16 + r) * 128 + col0 + j * 16] = acc[i][j][r];
    return;
  }

  if (bid >= 8224) {  // ---- expert-table cvt (only launched when bigws) ----
    const int c2 = bid - 8224;
    const float* src = (c2 >> 11) ? uE : dE;
    bf16* dst = (c2 >> 11) ? uEb : dEb;
    const long i = ((long)(c2 & 2047) * 256 + t) * 8;
    const f32x4 a = *(const f32x4*)(src + i);
    const f32x4 b = *(const f32x4*)(src + i + 4);
    bf16x8 o;
#pragma unroll
    for (int k = 0; k < 4; ++k) { o[k] = (bf16)a[k]; o[4 + k] = (bf16)b[k]; }
    *(bf16x8*)(dst + i) = o;
    return;
  }

  // ---- operand cvt: 8 elems/thread, 16B loads/stores ----
  const int c = bid - 32;
  const float* src;
  bf16* dst;
  switch (c >> 11) {
    case 0: src = X;  dst = Xb;  break;
    case 1: src = Wg; dst = Wgb; break;
    case 2: src = Wu; dst = Wub; break;
    default: src = Wd; dst = Wdb; break;
  }
  const long i = ((long)(c & 2047) * 256 + t) * 8;
  const f32x4 a = *(const f32x4*)(src + i);
  const f32x4 b = *(const f32x4*)(src + i + 4);
  bf16x8 o;
#pragma unroll
  for (int k = 0; k < 4; ++k) { o[k] = (bf16)a[k]; o[4 + k] = (bf16)b[k]; }
  *(bf16x8*)(dst + i) = o;
}

// ---------------- gate+up+silu GEMM (R1-verified 85 µs structure) ---------
__global__ void __launch_bounds__(256, 2) gemm_gu(
    const bf16* X, const bf16* Wg, const bf16* Wu, bf16* H) {
  constexpr int K = kHid, N = kInter;
  __shared__ bf16 sX[128 * 32];
  __shared__ bf16 sG[128 * 32];
  __shared__ bf16 sU[128 * 32];
  const int t = threadIdx.x;
  const int w = t >> 6;
  const int L = t & 63;
  const long m0 = (long)blockIdx.y * 128;
  const long n0 = (long)blockIdx.x * 128;
  const int wm = (w >> 1) * 64;
  const int wn = (w & 1) * 64;

  f32x4 accG[4][4], accU[4][4];
  const f32x4 fzero = {0.f, 0.f, 0.f, 0.f};
#pragma unroll
  for (int i = 0; i < 4; ++i)
#pragma unroll
    for (int j = 0; j < 4; ++j) { accG[i][j] = fzero; accU[i][j] = fzero; }

  const int r0 = t >> 2;
  const int ko = (t & 3) * 8;
  const bf16* gX0 = X + (m0 + r0) * K + ko;
  const bf16* gX1 = gX0 + (long)64 * K;
  const bf16* gG0 = Wg + (n0 + r0) * K + ko;
  const bf16* gG1 = gG0 + (long)64 * K;
  const bf16* gU0 = Wu + (n0 + r0) * K + ko;
  const bf16* gU1 = gU0 + (long)64 * K;
  bf16* lX0 = sX + w * 512;
  bf16* lX1 = sX + 2048 + w * 512;
  bf16* lG0 = sG + w * 512;
  bf16* lG1 = sG + 2048 + w * 512;
  bf16* lU0 = sU + w * 512;
  bf16* lU1 = sU + 2048 + w * 512;

  const int la = L & 15;
  const int lk = (L >> 4) * 8;
  const bf16* sXr = sX + (wm + la) * 32 + lk;
  const bf16* sGr = sG + (wn + la) * 32 + lk;
  const bf16* sUr = sU + (wn + la) * 32 + lk;

  for (int kt = 0; kt < K / 32; ++kt) {
    const long k0 = (long)kt << 5;
    GLDS16(gX0 + k0, lX0);
    GLDS16(gX1 + k0, lX1);
    GLDS16(gG0 + k0, lG0);
    GLDS16(gG1 + k0, lG1);
    GLDS16(gU0 + k0, lU0);
    GLDS16(gU1 + k0, lU1);
    __syncthreads();
    bf16x8 af[4], bg[4], bu[4];
#pragma unroll
    for (int i = 0; i < 4; ++i) {
      af[i] = *(const bf16x8*)(sXr + i * 512);
      bg[i] = *(const bf16x8*)(sGr + i * 512);
      bu[i] = *(const bf16x8*)(sUr + i * 512);
    }
#pragma unroll
    for (int i = 0; i < 4; ++i)
#pragma unroll
      for (int j = 0; j < 4; ++j) {
        accG[i][j] = __builtin_amdgcn_mfma_f32_16x16x32_bf16(af[i], bg[j],
                                                             accG[i][j], 0, 0, 0);
        accU[i][j] = __builtin_amdgcn_mfma_f32_16x16x32_bf16(af[i], bu[j],
                                                             accU[i][j], 0, 0, 0);
      }
    __syncthreads();
  }
  const long col0 = n0 + wn + la;
  const long row0 = m0 + wm + (L >> 4) * 4;
#pragma unroll
  for (int i = 0; i < 4; ++i)
#pragma unroll
    for (int j = 0; j < 4; ++j)
#pragma unroll
      for (int r = 0; r < 4; ++r) {
        const float g = accG[i][j][r];
        const float u = accU[i][j][r];
        H[(row0 + i * 16 + r) * N + col0 + j * 16] =
            (bf16)(g / (1.f + __expf(-g)) * u);
      }
}

// ---------------- down GEMM (128x128 tile, split-K=2, plain stores) -------
__global__ void __launch_bounds__(256, 2) gemm_down(
    const bf16* Hs, const bf16* Wd, float* out0, float* p1) {
  constexpr int K = kInter, N = kHid;
  __shared__ bf16 sA[128 * 32];
  __shared__ bf16 sB[128 * 32];
  const int t = threadIdx.x;
  const int w = t >> 6;
  const int L = t & 63;
  const long m0 = (long)blockIdx.y * 128;
  const long n0 = (long)blockIdx.x * 128;
  const long zb = (long)blockIdx.z * 2048;
  const int wm = (w >> 1) * 64;
  const int wn = (w & 1) * 64;

  f32x4 acc[4][4];
  const f32x4 fzero = {0.f, 0.f, 0.f, 0.f};
#pragma unroll
  for (int i = 0; i < 4; ++i)
#pragma unroll
    for (int j = 0; j < 4; ++j) acc[i][j] = fzero;

  const int r0 = t >> 2;
  const int ko = (t & 3) * 8;
  const bf16* gA0 = Hs + (m0 + r0) * K + zb + ko;
  const bf16* gA1 = gA0 + (long)64 * K;
  const bf16* gB0 = Wd + (n0 + r0) * K + zb + ko;
  const bf16* gB1 = gB0 + (long)64 * K;
  bf16* lA0 = sA + w * 512;
  bf16* lA1 = sA + 2048 + w * 512;
  bf16* lB0 = sB + w * 512;
  bf16* lB1 = sB + 2048 + w * 512;

  const int la = L & 15;
  const int lk = (L >> 4) * 8;
  const bf16* sAr = sA + (wm + la) * 32 + lk;
  const bf16* sBr = sB + (wn + la) * 32 + lk;

  for (int kt = 0; kt < 64; ++kt) {
    const long k0 = (long)kt << 5;
    GLDS16(gA0 + k0, lA0);
    GLDS16(gA1 + k0, lA1);
    GLDS16(gB0 + k0, lB0);
    GLDS16(gB1 + k0, lB1);
    __syncthreads();
    bf16x8 af[4], bfm[4];
#pragma unroll
    for (int i = 0; i < 4; ++i) {
      af[i] = *(const bf16x8*)(sAr + i * 512);
      bfm[i] = *(const bf16x8*)(sBr + i * 512);
    }
#pragma unroll
    for (int i = 0; i < 4; ++i)
#pragma unroll
      for (int j = 0; j < 4; ++j)
        acc[i][j] = __builtin_amdgcn_mfma_f32_16x16x32_bf16(af[i], bfm[j],
                                                            acc[i][j], 0, 0, 0);
    __syncthreads();
  }
  float* dst = (blockIdx.z == 0) ? out0 : p1;
  const long col0 = n0 + wn + la;
  const long row0 = m0 + wm + (L >> 4) * 4;
#pragma unroll
  for (int i = 0; i < 4; ++i)
#pragma unroll
    for (int j = 0; j < 4; ++j)
#pragma unroll
      for (int r = 0; r < 4; ++r)
        dst[(row0 + i * 16 + r) * N + col0 + j * 16] = acc[i][j][r];
}

// ---------------- routing + experts; out0 = out0 + p1 + experts -----------
// R12 structure: 2 tokens/block, 4 waves, wave (tok,h) walks experts
// 4h..4h+3. BT=1: bf16 tables, ALL 4 experts fully prefetched (16x16B
// loads upfront) + 4-way interleaved shfl reduce. BT=0: fp32 fallback.
template <int BT>
__global__ void __launch_bounds__(256) route_expert(
    const float* __restrict__ logits, const float* __restrict__ X,
    const float* __restrict__ dE, const float* __restrict__ uE,
    const bf16* __restrict__ dEb, const bf16* __restrict__ uEb,
    const float* __restrict__ p1, float* __restrict__ out0) {
  __shared__ float s_vals[2][128];
  __shared__ int s_idx[2][128];
  __shared__ float s_acc[2][16][64];
  const int w = threadIdx.x >> 6;
  const int L = threadIdx.x & 63;
  const int tok = w >> 1;       // 0..1
  const int h = w & 1;          // expert-half
  const int j = blockIdx.x * 2 + tok;

  const int half = (j & 1) * 64;
  const int rx = j >> 1;
  const float vx = logits[(long)rx * 128 + half + L];
  const float vy = logits[(long)(2048 + rx) * 128 + half + L];

  int rkx = 0, rky = 0;
  for (int m = 0; m < 64; ++m) {
    const float mx = __shfl(vx, m);
    const float my = __shfl(vy, m);
    rkx += (mx > vx) || (mx == vx && m < L);
    rky += (my > vy) || (my == vy && m < L);
  }
  rkx &= 63;
  rky &= 63;
  s_vals[tok][rkx] = vx;
  s_idx[tok][rkx] = L;
  s_vals[tok][64 + rky] = vy;
  s_idx[tok][64 + rky] = L;
  __syncthreads();

  int p = 0, q = 0;
  const bool valid = (L < 20);
  if (L < 8)       { p = L;      q = 0; }
  else if (L < 12) { p = L - 8;  q = 1; }
  else if (L < 14) { p = L - 12; q = 2; }
  else if (L < 16) { p = L - 14; q = 3; }
  else if (L < 20) { p = 0;      q = L - 12; }
  const float kNegBig = -3.0e38f;
  float myv = valid ? (s_vals[tok][p] + s_vals[tok][64 + q]) : kNegBig;
  int mypos = valid ? (p * 64 + q) : 0x7fffffff;

  float topv[8];
  int tope[8];
#pragma unroll
  for (int r = 0; r < 8; ++r) {
    float bv = myv;
    int bp = mypos;
#pragma unroll
    for (int d = 32; d > 0; d >>= 1) {
      const float ov = __shfl_xor(bv, d);
      const int op = __shfl_xor(bp, d);
      if (ov > bv || (ov == bv && op < bp)) { bv = ov; bp = op; }
    }
    topv[r] = bv;
    const int pp = (bp >> 6) & 127, qq = bp & 63;
    tope[r] = (s_idx[tok][pp] * 64 + s_idx[tok][64 + qq]) & 4095;
    if (mypos == bp) myv = kNegBig;
  }

  float e[8], wsum = 0.f;
#pragma unroll
  for (int r = 0; r < 8; ++r) {
    e[r] = __expf(topv[r] - topv[0]);
    wsum += e[r];
  }
  const float winv = 1.f / wsum;

  const long xoff = (long)j * kHid + L * 16;
  float xv[16], acc[16];
#pragma unroll
  for (int v4 = 0; v4 < 4; ++v4) {
    const f32x4 xl = *(const f32x4*)(X + xoff + v4 * 4);
#pragma unroll
    for (int i = 0; i < 4; ++i) { xv[v4 * 4 + i] = xl[i]; acc[v4 * 4 + i] = 0.f; }
  }

  const long lo16 = (long)L * 16;
  if (BT) {
    // ---- bf16 tables: ALL 4 experts prefetched (16 x 16B loads) ----
    const long eo0 = (long)tope[h * 4 + 0] * kHid + lo16;
    const long eo1 = (long)tope[h * 4 + 1] * kHid + lo16;
    const long eo2 = (long)tope[h * 4 + 2] * kHid + lo16;
    const long eo3 = (long)tope[h * 4 + 3] * kHid + lo16;
    const bf16x8 d00 = *(const bf16x8*)(dEb + eo0);
    const bf16x8 d01 = *(const bf16x8*)(dEb + eo0 + 8);
    const bf16x8 d10 = *(const bf16x8*)(dEb + eo1);
    const bf16x8 d11 = *(const bf16x8*)(dEb + eo1 + 8);
    const bf16x8 d20 = *(const bf16x8*)(dEb + eo2);
    const bf16x8 d21 = *(const bf16x8*)(dEb + eo2 + 8);
    const bf16x8 d30 = *(const bf16x8*)(dEb + eo3);
    const bf16x8 d31 = *(const bf16x8*)(dEb + eo3 + 8);
    const bf16x8 u00 = *(const bf16x8*)(uEb + eo0);
    const bf16x8 u01 = *(const bf16x8*)(uEb + eo0 + 8);
    const bf16x8 u10 = *(const bf16x8*)(uEb + eo1);
    const bf16x8 u11 = *(const bf16x8*)(uEb + eo1 + 8);
    const bf16x8 u20 = *(const bf16x8*)(uEb + eo2);
    const bf16x8 u21 = *(const bf16x8*)(uEb + eo2 + 8);
    const bf16x8 u30 = *(const bf16x8*)(uEb + eo3);
    const bf16x8 u31 = *(const bf16x8*)(uEb + eo3 + 8);

    float d0 = 0.f, d1 = 0.f, d2 = 0.f, d3 = 0.f;
#pragma unroll
    for (int i = 0; i < 8; ++i) {
      d0 += (float)d00[i] * xv[i] + (float)d01[i] * xv[8 + i];
      d1 += (float)d10[i] * xv[i] + (float)d11[i] * xv[8 + i];
      d2 += (float)d20[i] * xv[i] + (float)d21[i] * xv[8 + i];
      d3 += (float)d30[i] * xv[i] + (float)d31[i] * xv[8 + i];
    }
#pragma unroll
    for (int dd = 32; dd > 0; dd >>= 1) {  // 4-way interleaved reduce
      d0 += __shfl_xor(d0, dd);
      d1 += __shfl_xor(d1, dd);
      d2 += __shfl_xor(d2, dd);
      d3 += __shfl_xor(d3, dd);
    }
    const float w0 = d0 / (1.f + __expf(-d0)) * (e[h * 4 + 0] * winv);
    const float w1 = d1 / (1.f + __expf(-d1)) * (e[h * 4 + 1] * winv);
    const float w2 = d2 / (1.f + __expf(-d2)) * (e[h * 4 + 2] * winv);
    const float w3 = d3 / (1.f + __expf(-d3)) * (e[h * 4 + 3] * winv);
#pragma unroll
    for (int i = 0; i < 8; ++i) {
      acc[i]     += w0 * (float)u00[i] + w1 * (float)u10[i] +
                    w2 * (float)u20[i] + w3 * (float)u30[i];
      acc[8 + i] += w0 * (float)u01[i] + w1 * (float)u11[i] +
                    w2 * (float)u21[i] + w3 * (float)u31[i];
    }
  } else {
    // ---- fp32 tables (R12 path): 2-deep prefetch ----
    long eoA = (long)tope[h * 4 + 0] * kHid + lo16;
    f32x4 dA0 = *(const f32x4*)(dE + eoA);
    f32x4 dA1 = *(const f32x4*)(dE + eoA + 4);
    f32x4 dA2 = *(const f32x4*)(dE + eoA + 8);
    f32x4 dA3 = *(const f32x4*)(dE + eoA + 12);
    f32x4 uA0 = *(const f32x4*)(uE + eoA);
    f32x4 uA1 = *(const f32x4*)(uE + eoA + 4);
    f32x4 uA2 = *(const f32x4*)(uE + eoA + 8);
    f32x4 uA3 = *(const f32x4*)(uE + eoA + 12);
#pragma unroll
    for (int r = 0; r < 4; ++r) {
      f32x4 dB0, dB1, dB2, dB3, uB0, uB1, uB2, uB3;
      if (r < 3) {
        const long eoB = (long)tope[h * 4 + r + 1] * kHid + lo16;
        dB0 = *(const f32x4*)(dE + eoB);
        dB1 = *(const f32x4*)(dE + eoB + 4);
        dB2 = *(const f32x4*)(dE + eoB + 8);
        dB3 = *(const f32x4*)(dE + eoB + 12);
        uB0 = *(const f32x4*)(uE + eoB);
        uB1 = *(const f32x4*)(uE + eoB + 4);
        uB2 = *(const f32x4*)(uE + eoB + 8);
        uB3 = *(const f32x4*)(uE + eoB + 12);
      }
      float d = 0.f;
#pragma unroll
      for (int i = 0; i < 4; ++i) {
        d += dA0[i] * xv[i];
        d += dA1[i] * xv[4 + i];
        d += dA2[i] * xv[8 + i];
        d += dA3[i] * xv[12 + i];
      }
#pragma unroll
      for (int dd = 32; dd > 0; dd >>= 1) d += __shfl_xor(d, dd);
      const float ew = d / (1.f + __expf(-d)) * (e[h * 4 + r] * winv);
#pragma unroll
      for (int i = 0; i < 4; ++i) {
        acc[i]      += ew * uA0[i];
        acc[4 + i]  += ew * uA1[i];
        acc[8 + i]  += ew * uA2[i];
        acc[12 + i] += ew * uA3[i];
      }
      if (r < 3) {
        dA0 = dB0; dA1 = dB1; dA2 = dB2; dA3 = dB3;
        uA0 = uB0; uA1 = uB1; uA2 = uB2; uA3 = uB3;
      }
    }
  }

  // combine halves: h=1 publishes, h=0 reduces + final RMW
  if (h == 1) {
#pragma unroll
    for (int k = 0; k < 16; ++k) s_acc[tok][k][L] = acc[k];
  }
  __syncthreads();
  if (h == 0) {
#pragma unroll
    for (int k = 0; k < 16; ++k) acc[k] += s_acc[tok][k][L];
    float* po = out0 + xoff;
    const float* pp1 = p1 + xoff;
#pragma unroll
    for (int v4 = 0; v4 < 4; ++v4) {
      f32x4 ov = *(const f32x4*)(po + v4 * 4);
      const f32x4 pv = *(const f32x4*)(pp1 + v4 * 4);
#pragma unroll
      for (int i = 0; i < 4; ++i) ov[i] += pv[i] + acc[v4 * 4 + i];
      *(f32x4*)(po + v4 * 4) = ov;
    }
  }
}

extern "C" void kernel_launch(void* const* d_in, const int* in_sizes, int n_in,
                              void* d_out, int out_size, void* d_ws,
                              size_t ws_size, hipStream_t stream) {
  (void)in_sizes; (void)n_in; (void)out_size;
  const float* X  = (const float*)d_in[0];
  const float* Wg = (const float*)d_in[1];
  const float* Wu = (const float*)d_in[2];
  const float* Wd = (const float*)d_in[3];
  const float* Wr = (const float*)d_in[4];
  const float* dE = (const float*)d_in[5];
  const float* uE = (const float*)d_in[6];

  float* out0 = (float*)d_out;                  // (4096,1024) final
  float* out1 = out0 + (size_t)kTok * kHid;     // (2,4096,64) router logits

  // workspace layout:
  //   [0,32M)   wsH  H bf16
  //   [32,64M)  Xb/Wgb/Wub/Wdb (8 MiB each)
  //   [64,80M)  dEb/uEb bf16 tables (ONLY if ws_size >= 80 MiB)
  //   p1 (16 MiB fp32 down-partial) aliases Xb+Wgb AFTER gu consumed them
  bf16* wsH = (bf16*)d_ws;
  bf16* Xb  = wsH + (size_t)kTok * kInter;
  bf16* Wgb = Xb  + (size_t)kTok * kHid;
  bf16* Wub = Wgb + (size_t)kInter * kHid;
  bf16* Wdb = Wub + (size_t)kInter * kHid;
  float* p1 = (float*)Xb;  // 16 MiB spanning Xb+Wgb (dead after gemm_gu)
  const bool bigws = ws_size >= (size_t)80 * 1024 * 1024;
  bf16* dEb = (bf16*)((char*)d_ws + (size_t)64 * 1024 * 1024);
  bf16* uEb = (bf16*)((char*)d_ws + (size_t)72 * 1024 * 1024);

  dim3 blk(256);
  // 1) router (head) + operand cvt (+ table cvt when bigws)
  const int cvt_blocks = bigws ? 12320 : 8224;
  k_cvt_rt<<<dim3(cvt_blocks), blk, 0, stream>>>(
      X, Wg, Wu, Wd, Wr, dE, uE, Xb, Wgb, Wub, Wdb, dEb, uEb, out1);
  // 2) gu: H = silu(X*Wg^T)*(X*Wu^T) -> wsH  (proven 85 µs kernel)
  gemm_gu<<<dim3(32, 32), blk, 0, stream>>>(Xb, Wgb, Wub, wsH);
  // 3) down split-K=2, plain stores: z0 -> out0, z1 -> p1
  gemm_down<<<dim3(8, 32, 2), blk, 0, stream>>>(wsH, Wdb, out0, p1);
  // 4) routing + experts (bf16 tables + full 4-expert prefetch when bigws)
  if (bigws)
    route_expert<1><<<dim3(kTok / 2), blk, 0, stream>>>(out1, X, dE, uE, dEb,
                                                        uEb, p1, out0);
  else
    route_expert<0><<<dim3(kTok / 2), blk, 0, stream>>>(out1, X, dE, uE, dEb,
                                                        uEb, p1, out0);
}

// Round 16
// 314.877 us; speedup vs baseline: 1.0274x; 1.0274x over previous
//
#include <hip/hip_runtime.h>
#include <hip/hip_bf16.h>
#include <stdint.h>

typedef __bf16 bf16;
typedef __attribute__((ext_vector_type(8))) __bf16 bf16x8;
typedef __attribute__((ext_vector_type(4))) float f32x4;

static constexpr int kTok = 4096;    // B*S
static constexpr int kHid = 1024;
static constexpr int kInter = 4096;

// async global->LDS, 16B/lane. LDS arg must be wave-uniform base; HW adds
// lane*16. Global arg is per-lane.
#define GLDS16(g, l)                                                \
  __builtin_amdgcn_global_load_lds(                                 \
      (const __attribute__((address_space(1))) void*)(g),           \
      (__attribute__((address_space(3))) void*)(l), 16, 0, 0)

// counted-vmcnt wait + raw barrier: wave waits own outstanding loads, then
// barrier makes residency joint across waves. sched_barrier pins ordering.
#define WAIT_BAR(N)                                     \
  asm volatile("s_waitcnt vmcnt(" #N ")" ::: "memory"); \
  __builtin_amdgcn_s_barrier();                         \
  __builtin_amdgcn_sched_barrier(0)

// ---------------- fused: router GEMM (head) + fp32->bf16 convert ----------
// bid < 32       : router block (fp32 staged inline, reads X/Wr -> out1).
// 32 <= bid<8224 : cvt slice c=bid-32: c>>11 = 0:X 1:Wg 2:Wu 3:Wd.
// bid >= 8224    : expert-table cvt (dE/uE -> bf16), only when bigws.
__global__ void __launch_bounds__(256) k_cvt_rt(
    const float* X, const float* Wg, const float* Wu, const float* Wd,
    const float* Wr, const float* dE, const float* uE,
    bf16* Xb, bf16* Wgb, bf16* Wub, bf16* Wdb, bf16* dEb, bf16* uEb,
    float* out1) {
  __shared__ bf16 smem[8192];  // router only (16 KiB)
  const int bid = blockIdx.x;
  const int t = threadIdx.x;

  if (bid < 32) {
    // ---- router: C(4096x128) = X(4096x1024) * Wr(128x1024)^T ----
    const int w = t >> 6;
    const int L = t & 63;
    const int la = L & 15;
    const int lk = (L >> 4) * 8;
    bf16* sA = smem;           // 128x32
    bf16* sB = smem + 4096;    // 128x32
    const long m0 = (long)bid * 128;
    const int wm = (w >> 1) * 64;
    const int wn = (w & 1) * 64;
    const f32x4 fzero = {0.f, 0.f, 0.f, 0.f};
    f32x4 acc[4][4];
#pragma unroll
    for (int i = 0; i < 4; ++i)
#pragma unroll
      for (int j = 0; j < 4; ++j) acc[i][j] = fzero;

    const int c0 = t, c1 = t + 256;
    const long ar0 = m0 + (c0 >> 2), ar1 = m0 + (c1 >> 2);
    const long br0 = (c0 >> 2), br1 = (c1 >> 2);
    const int ko = (c0 & 3) * 8;
    const bf16* sAr = sA + (wm + la) * 32 + lk;
    const bf16* sBr = sB + (wn + la) * 32 + lk;

    for (int kt = 0; kt < 32; ++kt) {
      const long k0 = (long)kt << 5;
      bf16x8 av0, av1, bv0, bv1;
      {
        const f32x4 x0 = *(const f32x4*)(X + ar0 * kHid + k0 + ko);
        const f32x4 x1 = *(const f32x4*)(X + ar0 * kHid + k0 + ko + 4);
        const f32x4 y0 = *(const f32x4*)(X + ar1 * kHid + k0 + ko);
        const f32x4 y1 = *(const f32x4*)(X + ar1 * kHid + k0 + ko + 4);
        const f32x4 p0 = *(const f32x4*)(Wr + br0 * kHid + k0 + ko);
        const f32x4 p1 = *(const f32x4*)(Wr + br0 * kHid + k0 + ko + 4);
        const f32x4 q0 = *(const f32x4*)(Wr + br1 * kHid + k0 + ko);
        const f32x4 q1 = *(const f32x4*)(Wr + br1 * kHid + k0 + ko + 4);
#pragma unroll
        for (int i = 0; i < 4; ++i) {
          av0[i] = (bf16)x0[i]; av0[4 + i] = (bf16)x1[i];
          av1[i] = (bf16)y0[i]; av1[4 + i] = (bf16)y1[i];
          bv0[i] = (bf16)p0[i]; bv0[4 + i] = (bf16)p1[i];
          bv1[i] = (bf16)q0[i]; bv1[4 + i] = (bf16)q1[i];
        }
      }
      __syncthreads();
      *(bf16x8*)(sA + c0 * 8) = av0;
      *(bf16x8*)(sA + c1 * 8) = av1;
      *(bf16x8*)(sB + c0 * 8) = bv0;
      *(bf16x8*)(sB + c1 * 8) = bv1;
      __syncthreads();
      bf16x8 af[4], bfm[4];
#pragma unroll
      for (int i = 0; i < 4; ++i) {
        af[i] = *(const bf16x8*)(sAr + i * 512);
        bfm[i] = *(const bf16x8*)(sBr + i * 512);
      }
#pragma unroll
      for (int i = 0; i < 4; ++i)
#pragma unroll
        for (int j = 0; j < 4; ++j)
          acc[i][j] = __builtin_amdgcn_mfma_f32_16x16x32_bf16(
              af[i], bfm[j], acc[i][j], 0, 0, 0);
    }
    const long col0 = wn + la;
    const long row0 = m0 + wm + (L >> 4) * 4;
#pragma unroll
    for (int i = 0; i < 4; ++i)
#pragma unroll
      for (int j = 0; j < 4; ++j)
#pragma unroll
        for (int r = 0; r < 4; ++r)
          out1[(row0 + i * 16 + r) * 128 + col0 + j * 16] = acc[i][j][r];
    return;
  }

  if (bid >= 8224) {  // ---- expert-table cvt (only launched when bigws) ----
    const int c2 = bid - 8224;
    const float* src = (c2 >> 11) ? uE : dE;
    bf16* dst = (c2 >> 11) ? uEb : dEb;
    const long i = ((long)(c2 & 2047) * 256 + t) * 8;
    const f32x4 a = *(const f32x4*)(src + i);
    const f32x4 b = *(const f32x4*)(src + i + 4);
    bf16x8 o;
#pragma unroll
    for (int k = 0; k < 4; ++k) { o[k] = (bf16)a[k]; o[4 + k] = (bf16)b[k]; }
    *(bf16x8*)(dst + i) = o;
    return;
  }

  // ---- operand cvt: 8 elems/thread, 16B loads/stores ----
  const int c = bid - 32;
  const float* src;
  bf16* dst;
  switch (c >> 11) {
    case 0: src = X;  dst = Xb;  break;
    case 1: src = Wg; dst = Wgb; break;
    case 2: src = Wu; dst = Wub; break;
    default: src = Wd; dst = Wdb; break;
  }
  const long i = ((long)(c & 2047) * 256 + t) * 8;
  const f32x4 a = *(const f32x4*)(src + i);
  const f32x4 b = *(const f32x4*)(src + i + 4);
  bf16x8 o;
#pragma unroll
  for (int k = 0; k < 4; ++k) { o[k] = (bf16)a[k]; o[4 + k] = (bf16)b[k]; }
  *(bf16x8*)(dst + i) = o;
}

// ---------------- gate+up+silu GEMM: phase-pipelined, counted vmcnt -------
// Tile 256(M) x 128(N), BK=64, 1024 threads = 16 waves (4M x 4N),
// per-wave 64x32 per matrix -> accG/accU[4][2]. LDS 128 KiB:
//   sX[2 buf][2 khalf][256x32], sG/sU[2 buf][128x64].
// Per K-tile: 4 phases {G.ks0, U.ks0, G.ks1, U.ks1}, 8 MFMA each;
// one 16KB stage per phase for tile T+1 (order X0',G',X1',U').
// FIFO invariant (per-wave vmcnt): entry 4 in flight (T's X0,G,X1,U).
//   ph0 wait(2) -> X0,G of T landed. ph1 wait(1) -> X1,U of T landed.
//   ph2/ph3: residency already joint at ph1's barrier; no wait needed.
// Stages for T+2 only issue after next ph0 barrier => no buf overwrite race.
__global__ void __launch_bounds__(1024, 1) gemm_gu(
    const bf16* __restrict__ X, const bf16* __restrict__ Wg,
    const bf16* __restrict__ Wu, bf16* __restrict__ H) {
  constexpr int K = kHid;        // 1024
  constexpr int NT = K / 64;     // 16 K-tiles
  __shared__ bf16 sX[2][2][8192];  // [buf][khalf][256*32]  64 KiB
  __shared__ bf16 sG[2][8192];     // [buf][128*64]         32 KiB
  __shared__ bf16 sU[2][8192];     //                       32 KiB
  const int t = threadIdx.x;
  const int wid = t >> 6;
  const int L = t & 63;
  const int wm = wid >> 2;       // 0..3 (64-row strip)
  const int wn = wid & 3;        // 0..3 (32-col strip)
  const long m0 = (long)blockIdx.y * 256;
  const long n0 = (long)blockIdx.x * 128;

  f32x4 accG[4][2], accU[4][2];
  const f32x4 fzero = {0.f, 0.f, 0.f, 0.f};
#pragma unroll
  for (int i = 0; i < 4; ++i)
#pragma unroll
    for (int j = 0; j < 2; ++j) { accG[i][j] = fzero; accU[i][j] = fzero; }

  // staging source addresses (per-lane); K-offset added per call
  // X khalf [256][32]: thread covers row wid*16+(L>>2), col (L&3)*8
  const bf16* gX = X + (m0 + wid * 16 + (L >> 2)) * K + (L & 3) * 8;
  // G/U full tile [128][64]: row wid*8+(L>>3), col (L&7)*8
  const bf16* gG = Wg + (n0 + wid * 8 + (L >> 3)) * K + (L & 7) * 8;
  const bf16* gU = Wu + (n0 + wid * 8 + (L >> 3)) * K + (L & 7) * 8;
  const int lo = wid * 512;      // wave-uniform LDS element base

#define STG_X(b_, h_, kt_) GLDS16(gX + (kt_) * 64 + (h_) * 32, &sX[b_][h_][lo])
#define STG_G(b_, kt_)     GLDS16(gG + (kt_) * 64, &sG[b_][lo])
#define STG_U(b_, kt_)     GLDS16(gU + (kt_) * 64, &sU[b_][lo])

  const int la = L & 15;
  const int lk = (L >> 4) * 8;
  const int roA = (wm * 64 + la) * 32 + lk;        // within sX[b][ks]
  const int roB = (wn * 32 + la) * 64 + lk;        // within sG/sU[b], +ks*32

  // prologue: stage tile 0 in FIFO order X0,G,X1,U (4 in flight)
  STG_X(0, 0, 0);
  STG_G(0, 0);
  STG_X(0, 1, 0);
  STG_U(0, 0);

#define PH_LOAD_A(b_, ks_)                                   \
  _Pragma("unroll") for (int i = 0; i < 4; ++i)              \
      af[i] = *(const bf16x8*)(&sX[b_][ks_][roA] + i * 512);
#define PH_LOAD_B(dst_, s_, b_, ks_)                         \
  _Pragma("unroll") for (int j = 0; j < 2; ++j)              \
      dst_[j] = *(const bf16x8*)(&s_[b_][roB + (ks_) * 32] + j * 1024);
#define PH_MFMA(accM, bM)                                    \
  __builtin_amdgcn_s_setprio(1);                             \
  _Pragma("unroll") for (int i = 0; i < 4; ++i)              \
      _Pragma("unroll") for (int j = 0; j < 2; ++j)          \
          accM[i][j] = __builtin_amdgcn_mfma_f32_16x16x32_bf16( \
              af[i], bM[j], accM[i][j], 0, 0, 0);            \
  __builtin_amdgcn_s_setprio(0)

  for (int kt = 0; kt < NT - 1; ++kt) {
    const int b = kt & 1;
    const int nb = b ^ 1;
    bf16x8 af[4], bg[2], bu[2];
    // ph0: G kstep0
    WAIT_BAR(2);                 // X-k0(T), G(T) resident (joint)
    PH_LOAD_A(b, 0);
    PH_LOAD_B(bg, sG, b, 0);
    STG_X(nb, 0, kt + 1);
    PH_MFMA(accG, bg);
    // ph1: U kstep0
    WAIT_BAR(1);                 // X-k1(T), U(T) resident (joint)
    PH_LOAD_B(bu, sU, b, 0);
    STG_G(nb, kt + 1);
    PH_MFMA(accU, bu);
    // ph2: G kstep1 (no wait/barrier: residency joint since ph1)
    PH_LOAD_A(b, 1);
    PH_LOAD_B(bg, sG, b, 1);
    STG_X(nb, 1, kt + 1);
    PH_MFMA(accG, bg);
    // ph3: U kstep1
    PH_LOAD_B(bu, sU, b, 1);
    STG_U(nb, kt + 1);
    PH_MFMA(accU, bu);
  }
  {  // tail tile NT-1: no staging; drain 2 -> 0
    const int b = (NT - 1) & 1;
    bf16x8 af[4], bg[2], bu[2];
    WAIT_BAR(2);
    PH_LOAD_A(b, 0);
    PH_LOAD_B(bg, sG, b, 0);
    PH_MFMA(accG, bg);
    WAIT_BAR(0);
    PH_LOAD_B(bu, sU, b, 0);
    PH_MFMA(accU, bu);
    PH_LOAD_A(b, 1);
    PH_LOAD_B(bg, sG, b, 1);
    PH_MFMA(accG, bg);
    PH_LOAD_B(bu, sU, b, 1);
    PH_MFMA(accU, bu);
  }

  const long col0 = n0 + wn * 32 + la;
  const long row0 = m0 + wm * 64 + (L >> 4) * 4;
#pragma unroll
  for (int i = 0; i < 4; ++i)
#pragma unroll
    for (int j = 0; j < 2; ++j)
#pragma unroll
      for (int r = 0; r < 4; ++r) {
        const float g = accG[i][j][r];
        const float u = accU[i][j][r];
        H[(row0 + i * 16 + r) * kInter + col0 + j * 16] =
            (bf16)(g / (1.f + __expf(-g)) * u);
      }
}

// ---------------- down GEMM (128x128 tile, split-K=2, plain stores) -------
__global__ void __launch_bounds__(256, 2) gemm_down(
    const bf16* Hs, const bf16* Wd, float* out0, float* p1) {
  constexpr int K = kInter, N = kHid;
  __shared__ bf16 sA[128 * 32];
  __shared__ bf16 sB[128 * 32];
  const int t = threadIdx.x;
  const int w = t >> 6;
  const int L = t & 63;
  const long m0 = (long)blockIdx.y * 128;
  const long n0 = (long)blockIdx.x * 128;
  const long zb = (long)blockIdx.z * 2048;
  const int wm = (w >> 1) * 64;
  const int wn = (w & 1) * 64;

  f32x4 acc[4][4];
  const f32x4 fzero = {0.f, 0.f, 0.f, 0.f};
#pragma unroll
  for (int i = 0; i < 4; ++i)
#pragma unroll
    for (int j = 0; j < 4; ++j) acc[i][j] = fzero;

  const int r0 = t >> 2;
  const int ko = (t & 3) * 8;
  const bf16* gA0 = Hs + (m0 + r0) * K + zb + ko;
  const bf16* gA1 = gA0 + (long)64 * K;
  const bf16* gB0 = Wd + (n0 + r0) * K + zb + ko;
  const bf16* gB1 = gB0 + (long)64 * K;
  bf16* lA0 = sA + w * 512;
  bf16* lA1 = sA + 2048 + w * 512;
  bf16* lB0 = sB + w * 512;
  bf16* lB1 = sB + 2048 + w * 512;

  const int la = L & 15;
  const int lk = (L >> 4) * 8;
  const bf16* sAr = sA + (wm + la) * 32 + lk;
  const bf16* sBr = sB + (wn + la) * 32 + lk;

  for (int kt = 0; kt < 64; ++kt) {
    const long k0 = (long)kt << 5;
    GLDS16(gA0 + k0, lA0);
    GLDS16(gA1 + k0, lA1);
    GLDS16(gB0 + k0, lB0);
    GLDS16(gB1 + k0, lB1);
    __syncthreads();
    bf16x8 af[4], bfm[4];
#pragma unroll
    for (int i = 0; i < 4; ++i) {
      af[i] = *(const bf16x8*)(sAr + i * 512);
      bfm[i] = *(const bf16x8*)(sBr + i * 512);
    }
#pragma unroll
    for (int i = 0; i < 4; ++i)
#pragma unroll
      for (int j = 0; j < 4; ++j)
        acc[i][j] = __builtin_amdgcn_mfma_f32_16x16x32_bf16(af[i], bfm[j],
                                                            acc[i][j], 0, 0, 0);
    __syncthreads();
  }
  float* dst = (blockIdx.z == 0) ? out0 : p1;
  const long col0 = n0 + wn + la;
  const long row0 = m0 + wm + (L >> 4) * 4;
#pragma unroll
  for (int i = 0; i < 4; ++i)
#pragma unroll
    for (int j = 0; j < 4; ++j)
#pragma unroll
      for (int r = 0; r < 4; ++r)
        dst[(row0 + i * 16 + r) * N + col0 + j * 16] = acc[i][j][r];
}

// ---------------- routing + experts; out0 = out0 + p1 + experts -----------
// R12 structure: 2 tokens/block, 4 waves, wave (tok,h) walks experts
// 4h..4h+3. BT=1: bf16 tables, ALL 4 experts fully prefetched (16x16B
// loads upfront) + 4-way interleaved shfl reduce. BT=0: fp32 fallback.
template <int BT>
__global__ void __launch_bounds__(256) route_expert(
    const float* __restrict__ logits, const float* __restrict__ X,
    const float* __restrict__ dE, const float* __restrict__ uE,
    const bf16* __restrict__ dEb, const bf16* __restrict__ uEb,
    const float* __restrict__ p1, float* __restrict__ out0) {
  __shared__ float s_vals[2][128];
  __shared__ int s_idx[2][128];
  __shared__ float s_acc[2][16][64];
  const int w = threadIdx.x >> 6;
  const int L = threadIdx.x & 63;
  const int tok = w >> 1;       // 0..1
  const int h = w & 1;          // expert-half
  const int j = blockIdx.x * 2 + tok;

  const int half = (j & 1) * 64;
  const int rx = j >> 1;
  const float vx = logits[(long)rx * 128 + half + L];
  const float vy = logits[(long)(2048 + rx) * 128 + half + L];

  int rkx = 0, rky = 0;
  for (int m = 0; m < 64; ++m) {
    const float mx = __shfl(vx, m);
    const float my = __shfl(vy, m);
    rkx += (mx > vx) || (mx == vx && m < L);
    rky += (my > vy) || (my == vy && m < L);
  }
  rkx &= 63;
  rky &= 63;
  s_vals[tok][rkx] = vx;
  s_idx[tok][rkx] = L;
  s_vals[tok][64 + rky] = vy;
  s_idx[tok][64 + rky] = L;
  __syncthreads();

  int p = 0, q = 0;
  const bool valid = (L < 20);
  if (L < 8)       { p = L;      q = 0; }
  else if (L < 12) { p = L - 8;  q = 1; }
  else if (L < 14) { p = L - 12; q = 2; }
  else if (L < 16) { p = L - 14; q = 3; }
  else if (L < 20) { p = 0;      q = L - 12; }
  const float kNegBig = -3.0e38f;
  float myv = valid ? (s_vals[tok][p] + s_vals[tok][64 + q]) : kNegBig;
  int mypos = valid ? (p * 64 + q) : 0x7fffffff;

  float topv[8];
  int tope[8];
#pragma unroll
  for (int r = 0; r < 8; ++r) {
    float bv = myv;
    int bp = mypos;
#pragma unroll
    for (int d = 32; d > 0; d >>= 1) {
      const float ov = __shfl_xor(bv, d);
      const int op = __shfl_xor(bp, d);
      if (ov > bv || (ov == bv && op < bp)) { bv = ov; bp = op; }
    }
    topv[r] = bv;
    const int pp = (bp >> 6) & 127, qq = bp & 63;
    tope[r] = (s_idx[tok][pp] * 64 + s_idx[tok][64 + qq]) & 4095;
    if (mypos == bp) myv = kNegBig;
  }

  float e[8], wsum = 0.f;
#pragma unroll
  for (int r = 0; r < 8; ++r) {
    e[r] = __expf(topv[r] - topv[0]);
    wsum += e[r];
  }
  const float winv = 1.f / wsum;

  const long xoff = (long)j * kHid + L * 16;
  float xv[16], acc[16];
#pragma unroll
  for (int v4 = 0; v4 < 4; ++v4) {
    const f32x4 xl = *(const f32x4*)(X + xoff + v4 * 4);
#pragma unroll
    for (int i = 0; i < 4; ++i) { xv[v4 * 4 + i] = xl[i]; acc[v4 * 4 + i] = 0.f; }
  }

  const long lo16 = (long)L * 16;
  if (BT) {
    // ---- bf16 tables: ALL 4 experts prefetched (16 x 16B loads) ----
    const long eo0 = (long)tope[h * 4 + 0] * kHid + lo16;
    const long eo1 = (long)tope[h * 4 + 1] * kHid + lo16;
    const long eo2 = (long)tope[h * 4 + 2] * kHid + lo16;
    const long eo3 = (long)tope[h * 4 + 3] * kHid + lo16;
    const bf16x8 d00 = *(const bf16x8*)(dEb + eo0);
    const bf16x8 d01 = *(const bf16x8*)(dEb + eo0 + 8);
    const bf16x8 d10 = *(const bf16x8*)(dEb + eo1);
    const bf16x8 d11 = *(const bf16x8*)(dEb + eo1 + 8);
    const bf16x8 d20 = *(const bf16x8*)(dEb + eo2);
    const bf16x8 d21 = *(const bf16x8*)(dEb + eo2 + 8);
    const bf16x8 d30 = *(const bf16x8*)(dEb + eo3);
    const bf16x8 d31 = *(const bf16x8*)(dEb + eo3 + 8);
    const bf16x8 u00 = *(const bf16x8*)(uEb + eo0);
    const bf16x8 u01 = *(const bf16x8*)(uEb + eo0 + 8);
    const bf16x8 u10 = *(const bf16x8*)(uEb + eo1);
    const bf16x8 u11 = *(const bf16x8*)(uEb + eo1 + 8);
    const bf16x8 u20 = *(const bf16x8*)(uEb + eo2);
    const bf16x8 u21 = *(const bf16x8*)(uEb + eo2 + 8);
    const bf16x8 u30 = *(const bf16x8*)(uEb + eo3);
    const bf16x8 u31 = *(const bf16x8*)(uEb + eo3 + 8);

    float d0 = 0.f, d1 = 0.f, d2 = 0.f, d3 = 0.f;
#pragma unroll
    for (int i = 0; i < 8; ++i) {
      d0 += (float)d00[i] * xv[i] + (float)d01[i] * xv[8 + i];
      d1 += (float)d10[i] * xv[i] + (float)d11[i] * xv[8 + i];
      d2 += (float)d20[i] * xv[i] + (float)d21[i] * xv[8 + i];
      d3 += (float)d30[i] * xv[i] + (float)d31[i] * xv[8 + i];
    }
#pragma unroll
    for (int dd = 32; dd > 0; dd >>= 1) {  // 4-way interleaved reduce
      d0 += __shfl_xor(d0, dd);
      d1 += __shfl_xor(d1, dd);
      d2 += __shfl_xor(d2, dd);
      d3 += __shfl_xor(d3, dd);
    }
    const float w0 = d0 / (1.f + __expf(-d0)) * (e[h * 4 + 0] * winv);
    const float w1 = d1 / (1.f + __expf(-d1)) * (e[h * 4 + 1] * winv);
    const float w2 = d2 / (1.f + __expf(-d2)) * (e[h * 4 + 2] * winv);
    const float w3 = d3 / (1.f + __expf(-d3)) * (e[h * 4 + 3] * winv);
#pragma unroll
    for (int i = 0; i < 8; ++i) {
      acc[i]     += w0 * (float)u00[i] + w1 * (float)u10[i] +
                    w2 * (float)u20[i] + w3 * (float)u30[i];
      acc[8 + i] += w0 * (float)u01[i] + w1 * (float)u11[i] +
                    w2 * (float)u21[i] + w3 * (float)u31[i];
    }
  } else {
    // ---- fp32 tables (R12 path): 2-deep prefetch ----
    long eoA = (long)tope[h * 4 + 0] * kHid + lo16;
    f32x4 dA0 = *(const f32x4*)(dE + eoA);
    f32x4 dA1 = *(const f32x4*)(dE + eoA + 4);
    f32x4 dA2 = *(const f32x4*)(dE + eoA + 8);
    f32x4 dA3 = *(const f32x4*)(dE + eoA + 12);
    f32x4 uA0 = *(const f32x4*)(uE + eoA);
    f32x4 uA1 = *(const f32x4*)(uE + eoA + 4);
    f32x4 uA2 = *(const f32x4*)(uE + eoA + 8);
    f32x4 uA3 = *(const f32x4*)(uE + eoA + 12);
#pragma unroll
    for (int r = 0; r < 4; ++r) {
      f32x4 dB0, dB1, dB2, dB3, uB0, uB1, uB2, uB3;
      if (r < 3) {
        const long eoB = (long)tope[h * 4 + r + 1] * kHid + lo16;
        dB0 = *(const f32x4*)(dE + eoB);
        dB1 = *(const f32x4*)(dE + eoB + 4);
        dB2 = *(const f32x4*)(dE + eoB + 8);
        dB3 = *(const f32x4*)(dE + eoB + 12);
        uB0 = *(const f32x4*)(uE + eoB);
        uB1 = *(const f32x4*)(uE + eoB + 4);
        uB2 = *(const f32x4*)(uE + eoB + 8);
        uB3 = *(const f32x4*)(uE + eoB + 12);
      }
      float d = 0.f;
#pragma unroll
      for (int i = 0; i < 4; ++i) {
        d += dA0[i] * xv[i];
        d += dA1[i] * xv[4 + i];
        d += dA2[i] * xv[8 + i];
        d += dA3[i] * xv[12 + i];
      }
#pragma unroll
      for (int dd = 32; dd > 0; dd >>= 1) d += __shfl_xor(d, dd);
      const float ew = d / (1.f + __expf(-d)) * (e[h * 4 + r] * winv);
#pragma unroll
      for (int i = 0; i < 4; ++i) {
        acc[i]      += ew * uA0[i];
        acc[4 + i]  += ew * uA1[i];
        acc[8 + i]  += ew * uA2[i];
        acc[12 + i] += ew * uA3[i];
      }
      if (r < 3) {
        dA0 = dB0; dA1 = dB1; dA2 = dB2; dA3 = dB3;
        uA0 = uB0; uA1 = uB1; uA2 = uB2; uA3 = uB3;
      }
    }
  }

  // combine halves: h=1 publishes, h=0 reduces + final RMW
  if (h == 1) {
#pragma unroll
    for (int k = 0; k < 16; ++k) s_acc[tok][k][L] = acc[k];
  }
  __syncthreads();
  if (h == 0) {
#pragma unroll
    for (int k = 0; k < 16; ++k) acc[k] += s_acc[tok][k][L];
    float* po = out0 + xoff;
    const float* pp1 = p1 + xoff;
#pragma unroll
    for (int v4 = 0; v4 < 4; ++v4) {
      f32x4 ov = *(const f32x4*)(po + v4 * 4);
      const f32x4 pv = *(const f32x4*)(pp1 + v4 * 4);
#pragma unroll
      for (int i = 0; i < 4; ++i) ov[i] += pv[i] + acc[v4 * 4 + i];
      *(f32x4*)(po + v4 * 4) = ov;
    }
  }
}

extern "C" void kernel_launch(void* const* d_in, const int* in_sizes, int n_in,
                              void* d_out, int out_size, void* d_ws,
                              size_t ws_size, hipStream_t stream) {
  (void)in_sizes; (void)n_in; (void)out_size;
  const float* X  = (const float*)d_in[0];
  const float* Wg = (const float*)d_in[1];
  const float* Wu = (const float*)d_in[2];
  const float* Wd = (const float*)d_in[3];
  const float* Wr = (const float*)d_in[4];
  const float* dE = (const float*)d_in[5];
  const float* uE = (const float*)d_in[6];

  float* out0 = (float*)d_out;                  // (4096,1024) final
  float* out1 = out0 + (size_t)kTok * kHid;     // (2,4096,64) router logits

  // workspace layout:
  //   [0,32M)   wsH  H bf16
  //   [32,64M)  Xb/Wgb/Wub/Wdb (8 MiB each)
  //   [64,80M)  dEb/uEb bf16 tables (ONLY if ws_size >= 80 MiB)
  //   p1 (16 MiB fp32 down-partial) aliases Xb+Wgb AFTER gu consumed them
  bf16* wsH = (bf16*)d_ws;
  bf16* Xb  = wsH + (size_t)kTok * kInter;
  bf16* Wgb = Xb  + (size_t)kTok * kHid;
  bf16* Wub = Wgb + (size_t)kInter * kHid;
  bf16* Wdb = Wub + (size_t)kInter * kHid;
  float* p1 = (float*)Xb;  // 16 MiB spanning Xb+Wgb (dead after gemm_gu)
  const bool bigws = ws_size >= (size_t)80 * 1024 * 1024;
  bf16* dEb = (bf16*)((char*)d_ws + (size_t)64 * 1024 * 1024);
  bf16* uEb = (bf16*)((char*)d_ws + (size_t)72 * 1024 * 1024);

  dim3 blk(256);
  // 1) router (head) + operand cvt (+ table cvt when bigws)
  const int cvt_blocks = bigws ? 12320 : 8224;
  k_cvt_rt<<<dim3(cvt_blocks), blk, 0, stream>>>(
      X, Wg, Wu, Wd, Wr, dE, uE, Xb, Wgb, Wub, Wdb, dEb, uEb, out1);
  // 2) gu: phase-pipelined 256x128 tile, 1024 threads, counted vmcnt
  gemm_gu<<<dim3(32, 16), dim3(1024), 0, stream>>>(Xb, Wgb, Wub, wsH);
  // 3) down split-K=2, plain stores: z0 -> out0, z1 -> p1
  gemm_down<<<dim3(8, 32, 2), blk, 0, stream>>>(wsH, Wdb, out0, p1);
  // 4) routing + experts (bf16 tables + full 4-expert prefetch when bigws)
  if (bigws)
    route_expert<1><<<dim3(kTok / 2), blk, 0, stream>>>(out1, X, dE, uE, dEb,
                                                        uEb, p1, out0);
  else
    route_expert<0><<<dim3(kTok / 2), blk, 0, stream>>>(out1, X, dE, uE, dEb,
                                                        uEb, p1, out0);
}